// Round 4
// baseline (277.670 us; speedup 1.0000x reference)
//
#include <hip/hip_runtime.h>
#include <hip/hip_bf16.h>
#include <stdint.h>

#define B_ 2
#define N_ 4096
#define D_ 128
#define H_ 4
#define HID_ 32
#define EN_ 16
#define ALPHA_ 0.2f
#define S1_ 4
#define S2_ 4
#define LOG2E_ 1.4426950408889634f

typedef __attribute__((ext_vector_type(8))) _Float16 f16x8;
typedef __attribute__((ext_vector_type(4))) float f32x4;
typedef __attribute__((ext_vector_type(8))) unsigned short u16x8;

__device__ __forceinline__ unsigned short f2h(float v) {
    _Float16 h = (_Float16)v;
    return *(unsigned short*)&h;
}

// ---------- fused prep: blocks [0,2048) = adj->bitmask; [2048,3072) = layer-1 proj.
__global__ __launch_bounds__(256) void prep_kernel(
    const float* __restrict__ adj, unsigned long long* __restrict__ mask,
    const float* __restrict__ fea, const float* __restrict__ Wh,
    const float* __restrict__ a_heads,
    float* __restrict__ wh1, float* __restrict__ wh2,
    float* __restrict__ cmax1, unsigned short* __restrict__ whTt)
{
    __shared__ float xs[32][132];          // 16.9 KB
    __shared__ float WT[32][132];          // 16.9 KB
    __shared__ float Wa[2][128];
    __shared__ float as_[2 * HID_];
    __shared__ unsigned short ts[32][32];  // [d][r]
    __shared__ float rmax[32];
    const int tid = threadIdx.x;

    if (blockIdx.x < 2048) {               // ---- mask part ----
        const int b = blockIdx.x >> 10, ib = blockIdx.x & 1023;
        const int i = ib * 4 + (tid >> 6);
        const int lane = tid & 63;
        const float* ar = adj + ((size_t)b * N_ + i) * N_;
        unsigned long long* mrow = mask + ((size_t)b * N_ + i) * 64;
#pragma unroll 4
        for (int c = 0; c < 16; ++c) {
            float4 v = *(const float4*)(ar + c * 256 + lane * 4);
            unsigned long long b0 = __ballot(v.x != 0.f);
            unsigned long long b1 = __ballot(v.y != 0.f);
            unsigned long long b2 = __ballot(v.z != 0.f);
            unsigned long long b3 = __ballot(v.w != 0.f);
            if (lane == 0) {
                ulonglong2 w01 = {b0, b1}, w23 = {b2, b3};
                *(ulonglong2*)(mrow + c * 4) = w01;
                *(ulonglong2*)(mrow + c * 4 + 2) = w23;
            }
        }
        return;
    }
    // ---- proj1 part: 32 rows x 32 cols, one head ----
    const int l0 = blockIdx.x - 2048;
    const int ib = l0 & 127, h = (l0 >> 7) & 3, b = l0 >> 9;
    const int i0 = ib * 32;
    const float* Wp = Wh + (size_t)h * D_ * HID_;
    for (int l = tid; l < 1024; l += 256) {          // W[k][d] -> WT[d][k]
        float4 w4 = *(const float4*)(Wp + l * 4);
        int k = l >> 3, d = (l & 7) * 4;
        WT[d][k] = w4.x; WT[d + 1][k] = w4.y; WT[d + 2][k] = w4.z; WT[d + 3][k] = w4.w;
    }
    if (tid < 2 * HID_) as_[tid] = a_heads[h * 2 * HID_ + tid];
    const float* xp = fea + ((size_t)b * N_ + i0) * D_;
    for (int l = tid; l < 1024; l += 256) {
        int r = l >> 5, k4 = (l & 31) * 4;
        *(float4*)&xs[r][k4] = *(const float4*)(xp + r * D_ + k4);
    }
    __syncthreads();
    // Wa[j][k] = sum_d W[k][d]*a[j*HID+d]
    {
        const int k = tid & 127, j = tid >> 7;
        const float* wr = Wp + k * HID_;
        const float* aw = &as_[j * HID_];
        float s = 0.f;
#pragma unroll
        for (int d = 0; d < HID_; d += 4) {
            float4 w4 = *(const float4*)(wr + d);
            s += w4.x * aw[d] + w4.y * aw[d + 1] + w4.z * aw[d + 2] + w4.w * aw[d + 3];
        }
        Wa[j][k] = s;
    }
    const int c = tid & 15, rg = (tid >> 4) * 2;     // rows rg,rg+1; cols c,c+16
    float a0[2] = {0.f, 0.f}, a1[2] = {0.f, 0.f};
#pragma unroll 8
    for (int k = 0; k < D_; k += 4) {
        float4 w0 = *(float4*)&WT[c][k];
        float4 w1 = *(float4*)&WT[c + 16][k];
#pragma unroll
        for (int i = 0; i < 2; ++i) {
            float4 x4 = *(float4*)&xs[rg + i][k];
            a0[i] += x4.x * w0.x + x4.y * w0.y + x4.z * w0.z + x4.w * w0.w;
            a1[i] += x4.x * w1.x + x4.y * w1.y + x4.z * w1.z + x4.w * w1.w;
        }
    }
#pragma unroll
    for (int i = 0; i < 2; ++i) {
        ts[c][rg + i] = f2h(a0[i]);
        ts[c + 16][rg + i] = f2h(a1[i]);
    }
    __syncthreads();                                 // Wa + ts ready
    {
        const int row = tid >> 3, q = tid & 7;       // 32 rows x 8 threads
        float d1 = 0.f, d2 = 0.f;
#pragma unroll
        for (int k = q * 16; k < q * 16 + 16; k += 4) {
            float4 x4 = *(float4*)&xs[row][k];
            float4 u = *(float4*)&Wa[0][k];
            float4 v = *(float4*)&Wa[1][k];
            d1 += x4.x * u.x + x4.y * u.y + x4.z * u.z + x4.w * u.w;
            d2 += x4.x * v.x + x4.y * v.y + x4.z * v.z + x4.w * v.w;
        }
        d1 += __shfl_xor(d1, 1); d1 += __shfl_xor(d1, 2); d1 += __shfl_xor(d1, 4);
        d2 += __shfl_xor(d2, 1); d2 += __shfl_xor(d2, 2); d2 += __shfl_xor(d2, 4);
        if (q == 0) {
            const size_t o = (size_t)(b * H_ + h) * N_ + i0 + row;
            wh1[o] = d1 * LOG2E_;
            wh2[o] = d2 * LOG2E_;
            rmax[row] = d2 * LOG2E_;
        }
    }
    __syncthreads();
    if (tid < 128) {                                 // whT tile out (1024 halfwords)
        const int d = tid >> 2, part = (tid & 3) * 8;
        unsigned short* dst = whTt + ((size_t)(b * H_ + h) * 64 + (i0 >> 6)) * 2048
                            + d * 64 + (i0 & 63) + part;
        *(u16x8*)dst = *(u16x8*)&ts[d][part];
    }
    if (tid < 32) {
        float mx = rmax[tid];
#pragma unroll
        for (int off = 16; off; off >>= 1) mx = fmaxf(mx, __shfl_xor(mx, off));
        if (tid == 0) cmax1[(size_t)(b * H_ + h) * 128 + ib] = mx;
    }
}

// ---------- layer-1 fused MFMA attention.
// PROBE (R4): __launch_bounds__(256,3) instead of (256,4). VGPR cap 128->~170.
// If the hot loop was spilling under the 128 cap (explains why two rounds of
// ALU reduction were neutral), spills vanish -> large win. If latency-bound,
// occupancy 16->12 waves/CU costs ~5-15us -> pivot to prefetch next round.
__global__ __launch_bounds__(256, 3) void attn1_kernel(
    const unsigned long long* __restrict__ mask, const unsigned short* __restrict__ whT,
    const float* __restrict__ wh1, const float* __restrict__ wh2,
    const float* __restrict__ cmax1,
    float* __restrict__ x2p, float* __restrict__ l1p)
{
    __shared__ unsigned long long mask_s[32][17];
    __shared__ float Btab[H_][2][1024];    // 32 KB: per-head (B, B') tables
    const int b = blockIdx.z, split = blockIdx.y, i0 = blockIdx.x * 32;
    const int tid = threadIdx.x, lane = tid & 63, h = tid >> 6;
    const int m = lane & 15, quad = lane >> 4;
    {
        const int r = tid >> 3, w = (tid & 7) * 2;
        ulonglong2 mw = *(const ulonglong2*)(mask + ((size_t)b * N_ + i0 + r) * 64
                                             + split * 16 + w);
        mask_s[r][w] = mw.x; mask_s[r][w + 1] = mw.y;
    }
    const float* cm = cmax1 + (size_t)(b * H_ + h) * 128;
    float Mh = fmaxf(cm[lane], cm[lane + 64]);
#pragma unroll
    for (int off = 32; off; off >>= 1) Mh = fmaxf(Mh, __shfl_xor(Mh, off));
    const size_t bhN = (size_t)(b * H_ + h) * N_;
    // fill this head's (B, B') table: 1024 j's, 16 per lane
    const float* w2g = wh2 + bhN + split * 1024;
#pragma unroll
    for (int g = 0; g < 4; ++g) {
        float4 v = *(const float4*)(w2g + g * 256 + lane * 4);
        float4 eb, ep;
        eb.x = __builtin_amdgcn_exp2f(v.x - Mh);
        eb.y = __builtin_amdgcn_exp2f(v.y - Mh);
        eb.z = __builtin_amdgcn_exp2f(v.z - Mh);
        eb.w = __builtin_amdgcn_exp2f(v.w - Mh);
        ep.x = __builtin_amdgcn_exp2f(ALPHA_ * (v.x - Mh));
        ep.y = __builtin_amdgcn_exp2f(ALPHA_ * (v.y - Mh));
        ep.z = __builtin_amdgcn_exp2f(ALPHA_ * (v.z - Mh));
        ep.w = __builtin_amdgcn_exp2f(ALPHA_ * (v.w - Mh));
        *(float4*)&Btab[h][0][g * 256 + lane * 4] = eb;
        *(float4*)&Btab[h][1][g * 256 + lane * 4] = ep;
    }
    const float w1r0 = wh1[bhN + i0 + m];
    const float w1r1 = wh1[bhN + i0 + 16 + m];
    const float sb0 = w1r0 + Mh, sb1 = w1r1 + Mh;
    const float mr0 = fmaxf(sb0, ALPHA_ * sb0);
    const float mr1 = fmaxf(sb1, ALPHA_ * sb1);
    const float th0 = -w1r0, th1 = -w1r1;
    const float Fp0 = __builtin_amdgcn_exp2f(sb0 - mr0);
    const float Fn0 = __builtin_amdgcn_exp2f(ALPHA_ * sb0 - mr0);
    const float Fp1 = __builtin_amdgcn_exp2f(sb1 - mr1);
    const float Fn1 = __builtin_amdgcn_exp2f(ALPHA_ * sb1 - mr1);
    const float* wvb = wh2 + bhN + split * 1024 + quad * 8;
    const unsigned short* bpb = whT + (size_t)(b * H_ + h) * 131072
                              + (size_t)split * 16 * 2048 + m * 64 + quad * 8;
    f32x4 a00 = {0.f,0.f,0.f,0.f}, a01 = {0.f,0.f,0.f,0.f}, a02 = {0.f,0.f,0.f,0.f};
    f32x4 a10 = {0.f,0.f,0.f,0.f}, a11 = {0.f,0.f,0.f,0.f}, a12 = {0.f,0.f,0.f,0.f};
    f16x8 ones;
#pragma unroll
    for (int q = 0; q < 8; ++q) ones[q] = (_Float16)1.0f;
    __syncthreads();

    for (int c = 0; c < 4; ++c) {
#pragma unroll
        for (int q4 = 0; q4 < 4; ++q4) {
            const int t = c * 4 + q4;
            const int half = q4 >> 1;                // dword half of the 64-bit word
            unsigned int pw0, pw1, pw2, pw3, qw0, qw1, qw2, qw3;
            pw0 = ((const unsigned int*)&mask_s[m][c*4+0])[half];
            pw1 = ((const unsigned int*)&mask_s[m][c*4+1])[half];
            pw2 = ((const unsigned int*)&mask_s[m][c*4+2])[half];
            pw3 = ((const unsigned int*)&mask_s[m][c*4+3])[half];
            qw0 = ((const unsigned int*)&mask_s[m+16][c*4+0])[half];
            qw1 = ((const unsigned int*)&mask_s[m+16][c*4+1])[half];
            qw2 = ((const unsigned int*)&mask_s[m+16][c*4+2])[half];
            qw3 = ((const unsigned int*)&mask_s[m+16][c*4+3])[half];
            const unsigned short* bp = bpb + (size_t)t * 2048;
            const float* nw = wvb + t * 64;
#pragma unroll
            for (int ks = 0; ks < 2; ++ks) {
                f16x8 bb0 = *(const f16x8*)(bp + ks * 32);
                f16x8 bb1 = *(const f16x8*)(bp + 1024 + ks * 32);
                float wv8[8];
                *(float4*)&wv8[0] = *(const float4*)(nw + ks * 32);
                *(float4*)&wv8[4] = *(const float4*)(nw + ks * 32 + 4);
                float Bj[8], Bp8[8];
                {
                    const float* Bb = &Btab[h][0][t * 64 + ks * 32 + quad * 8];
                    const float* Pb = &Btab[h][1][t * 64 + ks * 32 + quad * 8];
                    *(float4*)&Bj[0]  = *(const float4*)Bb;
                    *(float4*)&Bj[4]  = *(const float4*)(Bb + 4);
                    *(float4*)&Bp8[0] = *(const float4*)Pb;
                    *(float4*)&Bp8[4] = *(const float4*)(Pb + 4);
                }
                const int sh = ((16 * q4 + 8 * ks) & 31) + 2 * quad;
                const unsigned int gp0 = (pw0 >> sh) & 3u;
                const unsigned int gp1 = (pw1 >> sh) & 3u;
                const unsigned int gp2 = (pw2 >> sh) & 3u;
                const unsigned int gp3 = (pw3 >> sh) & 3u;
                const unsigned int gq0 = (qw0 >> sh) & 3u;
                const unsigned int gq1 = (qw1 >> sh) & 3u;
                const unsigned int gq2 = (qw2 >> sh) & 3u;
                const unsigned int gq3 = (qw3 >> sh) & 3u;
                f16x8 af0, af1;
#pragma unroll
                for (int qq = 0; qq < 4; ++qq) {
                    float r0p[2], r1p[2];
#pragma unroll
                    for (int cc = 0; cc < 2; ++cc) {
                        const int jj = qq * 2 + cc;
                        const unsigned int bsel = 1u << (jj >> 2);
                        const unsigned int gp = (jj&3)==0?gp0:(jj&3)==1?gp1:(jj&3)==2?gp2:gp3;
                        const unsigned int gq = (jj&3)==0?gq0:(jj&3)==1?gq1:(jj&3)==2?gq2:gq3;
                        const float w2v = wv8[jj];
                        float v0s = (w2v > th0) ? Fp0 * Bj[jj] : Fn0 * Bp8[jj];
                        r0p[cc] = ((gp & bsel) == 0u || w2v == th0) ? 0.f : v0s;
                        float v1s = (w2v > th1) ? Fp1 * Bj[jj] : Fn1 * Bp8[jj];
                        r1p[cc] = ((gq & bsel) == 0u || w2v == th1) ? 0.f : v1s;
                    }
                    auto pr0 = __builtin_amdgcn_cvt_pkrtz(r0p[0], r0p[1]);
                    af0[qq*2] = (_Float16)pr0[0]; af0[qq*2+1] = (_Float16)pr0[1];
                    auto pr1 = __builtin_amdgcn_cvt_pkrtz(r1p[0], r1p[1]);
                    af1[qq*2] = (_Float16)pr1[0]; af1[qq*2+1] = (_Float16)pr1[1];
                }
                a00 = __builtin_amdgcn_mfma_f32_16x16x32_f16(af0, bb0, a00, 0, 0, 0);
                a01 = __builtin_amdgcn_mfma_f32_16x16x32_f16(af0, bb1, a01, 0, 0, 0);
                a02 = __builtin_amdgcn_mfma_f32_16x16x32_f16(af0, ones, a02, 0, 0, 0);
                a10 = __builtin_amdgcn_mfma_f32_16x16x32_f16(af1, bb0, a10, 0, 0, 0);
                a11 = __builtin_amdgcn_mfma_f32_16x16x32_f16(af1, bb1, a11, 0, 0, 0);
                a12 = __builtin_amdgcn_mfma_f32_16x16x32_f16(af1, ones, a12, 0, 0, 0);
            }
        }
    }
    float* xp = x2p + (((size_t)split * B_ + b) * N_ + i0) * D_ + h * HID_;
#pragma unroll
    for (int reg = 0; reg < 4; ++reg) {
        const int row = quad * 4 + reg;
        xp[(size_t)row * D_ + m] = a00[reg];
        xp[(size_t)row * D_ + 16 + m] = a01[reg];
        xp[(size_t)(row + 16) * D_ + m] = a10[reg];
        xp[(size_t)(row + 16) * D_ + 16 + m] = a11[reg];
    }
    if (m == 0) {
        float* lp = l1p + (((size_t)split * B_ + b) * N_ + i0) * H_ + h;
#pragma unroll
        for (int reg = 0; reg < 4; ++reg) {
            lp[(size_t)(quad * 4 + reg) * H_] = a02[reg];
            lp[(size_t)(quad * 4 + reg + 16) * H_] = a12[reg];
        }
    }
}

// ---------- merged layer-2 projection (unchanged)
__global__ __launch_bounds__(256) void proj2_kernel(
    const float* __restrict__ x2p, const float* __restrict__ l1p,
    const float* __restrict__ Wl, const float* __restrict__ a_last,
    float* __restrict__ wh1b, float* __restrict__ wh2b,
    float* __restrict__ cmax2, unsigned short* __restrict__ whT2t)
{
    __shared__ float Ws[D_ * EN_];
    __shared__ float xs[16][D_];
    __shared__ float as_[2 * EN_];
    __shared__ unsigned short ts[EN_][16];
    __shared__ float rmax[16];
    const int b = blockIdx.y, i0 = blockIdx.x * 16, tid = threadIdx.x;
    for (int idx = tid * 4; idx < D_ * EN_; idx += 1024)
        *(float4*)&Ws[idx] = *(const float4*)(Wl + idx);
    if (tid < 2 * EN_) as_[tid] = a_last[tid];
    for (int idx = tid * 4; idx < 16 * D_; idx += 1024) {
        const int r = idx >> 7, hd = idx & 127, h = hd >> 5;
        float4 v = {0.f, 0.f, 0.f, 0.f};
        float l = 0.f;
#pragma unroll
        for (int s = 0; s < S1_; ++s) {
            const size_t gi = ((size_t)s * B_ + b) * N_ + i0 + r;
            float4 p = *(const float4*)(x2p + gi * D_ + hd);
            v.x += p.x; v.y += p.y; v.z += p.z; v.w += p.w;
            l += l1p[gi * H_ + h];
        }
        float linv = 1.f / fmaxf(l, 1e-30f);
        float o0 = v.x * linv, o1 = v.y * linv, o2 = v.z * linv, o3 = v.w * linv;
        xs[r][hd]     = o0 > 0.f ? o0 : expm1f(o0);
        xs[r][hd + 1] = o1 > 0.f ? o1 : expm1f(o1);
        xs[r][hd + 2] = o2 > 0.f ? o2 : expm1f(o2);
        xs[r][hd + 3] = o3 > 0.f ? o3 : expm1f(o3);
    }
    __syncthreads();
    const int r = tid >> 4, e = tid & 15;
    float acc = 0.f;
#pragma unroll 8
    for (int k = 0; k < D_; ++k) acc += xs[r][k] * Ws[k * EN_ + e];
    ts[e][r] = f2h(acc);
    float d1 = acc * as_[e], d2 = acc * as_[EN_ + e];
#pragma unroll
    for (int off = 8; off; off >>= 1) {
        d1 += __shfl_xor(d1, off);
        d2 += __shfl_xor(d2, off);
    }
    d1 *= LOG2E_; d2 *= LOG2E_;
    if (e == 0) {
        wh1b[(size_t)b * N_ + i0 + r] = d1;
        wh2b[(size_t)b * N_ + i0 + r] = d2;
        rmax[r] = d2;
    }
    __syncthreads();
    if (tid < EN_) {
        unsigned short* dst = whT2t + (size_t)b * 65536
                            + (i0 >> 6) * 1024 + tid * 64 + (i0 & 63);
        *(u16x8*)dst = *(u16x8*)&ts[tid][0];
        *(u16x8*)(dst + 8) = *(u16x8*)&ts[tid][8];
    }
    if (tid == 0) {
        float mx = rmax[0];
#pragma unroll
        for (int k = 1; k < 16; ++k) mx = fmaxf(mx, rmax[k]);
        cmax2[(size_t)b * 256 + blockIdx.x] = mx;
    }
}

// ---------- layer-2 fused MFMA attention (control: unchanged at (256,4))
__global__ __launch_bounds__(256, 4) void attn2_kernel(
    const unsigned long long* __restrict__ mask, const unsigned short* __restrict__ whT2,
    const float* __restrict__ wh1b, const float* __restrict__ wh2b,
    const float* __restrict__ cmax2,
    float* __restrict__ outp, float* __restrict__ outlp)
{
    __shared__ unsigned long long mask_s[32][17];
    __shared__ float accred[4][32][17];
    __shared__ float lred[4][32];
    __shared__ float Btab2[2][1024];       // 8 KB
    const int b = blockIdx.z, split = blockIdx.y, i0 = blockIdx.x * 32;
    const int tid = threadIdx.x, lane = tid & 63, wv = tid >> 6;
    const int m = lane & 15, quad = lane >> 4;
    {
        const int r = tid >> 3, w = (tid & 7) * 2;
        ulonglong2 mw = *(const ulonglong2*)(mask + ((size_t)b * N_ + i0 + r) * 64
                                             + split * 16 + w);
        mask_s[r][w] = mw.x; mask_s[r][w + 1] = mw.y;
    }
    const float* cm = cmax2 + (size_t)b * 256;
    float4 c0 = *(const float4*)(cm + lane * 4);
    float Mh = fmaxf(fmaxf(c0.x, c0.y), fmaxf(c0.z, c0.w));
#pragma unroll
    for (int off = 32; off; off >>= 1) Mh = fmaxf(Mh, __shfl_xor(Mh, off));
    // fill shared (B, B') table: 4 j's per thread
    {
        float4 v = *(const float4*)(wh2b + (size_t)b * N_ + split * 1024 + tid * 4);
        float4 eb, ep;
        eb.x = __builtin_amdgcn_exp2f(v.x - Mh);
        eb.y = __builtin_amdgcn_exp2f(v.y - Mh);
        eb.z = __builtin_amdgcn_exp2f(v.z - Mh);
        eb.w = __builtin_amdgcn_exp2f(v.w - Mh);
        ep.x = __builtin_amdgcn_exp2f(ALPHA_ * (v.x - Mh));
        ep.y = __builtin_amdgcn_exp2f(ALPHA_ * (v.y - Mh));
        ep.z = __builtin_amdgcn_exp2f(ALPHA_ * (v.z - Mh));
        ep.w = __builtin_amdgcn_exp2f(ALPHA_ * (v.w - Mh));
        *(float4*)&Btab2[0][tid * 4] = eb;
        *(float4*)&Btab2[1][tid * 4] = ep;
    }
    const float w1r0 = wh1b[(size_t)b * N_ + i0 + m];
    const float w1r1 = wh1b[(size_t)b * N_ + i0 + 16 + m];
    const float sb0 = w1r0 + Mh, sb1 = w1r1 + Mh;
    const float mr0 = fmaxf(sb0, ALPHA_ * sb0);
    const float mr1 = fmaxf(sb1, ALPHA_ * sb1);
    const float th0 = -w1r0, th1 = -w1r1;
    const float Fp0 = __builtin_amdgcn_exp2f(sb0 - mr0);
    const float Fn0 = __builtin_amdgcn_exp2f(ALPHA_ * sb0 - mr0);
    const float Fp1 = __builtin_amdgcn_exp2f(sb1 - mr1);
    const float Fn1 = __builtin_amdgcn_exp2f(ALPHA_ * sb1 - mr1);
    const unsigned short* wTb = whT2 + (size_t)b * 65536
                              + (size_t)(split * 16 + wv * 4) * 1024 + m * 64 + quad * 8;
    const float* wvb = wh2b + (size_t)b * N_ + split * 1024 + wv * 256 + quad * 8;
    f32x4 a0 = {0.f,0.f,0.f,0.f}, a1 = {0.f,0.f,0.f,0.f};
    f32x4 l0 = {0.f,0.f,0.f,0.f}, l1 = {0.f,0.f,0.f,0.f};
    f16x8 ones;
#pragma unroll
    for (int q = 0; q < 8; ++q) ones[q] = (_Float16)1.0f;
    __syncthreads();
#pragma unroll
    for (int q4 = 0; q4 < 4; ++q4) {
        const int half = q4 >> 1;
        unsigned int pw0, pw1, pw2, pw3, qw0, qw1, qw2, qw3;
        pw0 = ((const unsigned int*)&mask_s[m][wv*4+0])[half];
        pw1 = ((const unsigned int*)&mask_s[m][wv*4+1])[half];
        pw2 = ((const unsigned int*)&mask_s[m][wv*4+2])[half];
        pw3 = ((const unsigned int*)&mask_s[m][wv*4+3])[half];
        qw0 = ((const unsigned int*)&mask_s[m+16][wv*4+0])[half];
        qw1 = ((const unsigned int*)&mask_s[m+16][wv*4+1])[half];
        qw2 = ((const unsigned int*)&mask_s[m+16][wv*4+2])[half];
        qw3 = ((const unsigned int*)&mask_s[m+16][wv*4+3])[half];
        const unsigned short* bp = wTb + (size_t)q4 * 1024;
        const float* nw = wvb + q4 * 64;
#pragma unroll
        for (int ks = 0; ks < 2; ++ks) {
            f16x8 bb = *(const f16x8*)(bp + ks * 32);
            float wv8[8];
            *(float4*)&wv8[0] = *(const float4*)(nw + ks * 32);
            *(float4*)&wv8[4] = *(const float4*)(nw + ks * 32 + 4);
            float Bj[8], Bp8[8];
            {
                const float* Bb = &Btab2[0][wv * 256 + q4 * 64 + ks * 32 + quad * 8];
                const float* Pb = &Btab2[1][wv * 256 + q4 * 64 + ks * 32 + quad * 8];
                *(float4*)&Bj[0]  = *(const float4*)Bb;
                *(float4*)&Bj[4]  = *(const float4*)(Bb + 4);
                *(float4*)&Bp8[0] = *(const float4*)Pb;
                *(float4*)&Bp8[4] = *(const float4*)(Pb + 4);
            }
            const int sh = ((16 * q4 + 8 * ks) & 31) + 2 * quad;
            const unsigned int gp0 = (pw0 >> sh) & 3u;
            const unsigned int gp1 = (pw1 >> sh) & 3u;
            const unsigned int gp2 = (pw2 >> sh) & 3u;
            const unsigned int gp3 = (pw3 >> sh) & 3u;
            const unsigned int gq0 = (qw0 >> sh) & 3u;
            const unsigned int gq1 = (qw1 >> sh) & 3u;
            const unsigned int gq2 = (qw2 >> sh) & 3u;
            const unsigned int gq3 = (qw3 >> sh) & 3u;
            f16x8 af0, af1;
#pragma unroll
            for (int qq = 0; qq < 4; ++qq) {
                float r0p[2], r1p[2];
#pragma unroll
                for (int cc = 0; cc < 2; ++cc) {
                    const int jj = qq * 2 + cc;
                    const unsigned int bsel = 1u << (jj >> 2);
                    const unsigned int gp = (jj&3)==0?gp0:(jj&3)==1?gp1:(jj&3)==2?gp2:gp3;
                    const unsigned int gq = (jj&3)==0?gq0:(jj&3)==1?gq1:(jj&3)==2?gq2:gq3;
                    const float w2v = wv8[jj];
                    float v0s = (w2v > th0) ? Fp0 * Bj[jj] : Fn0 * Bp8[jj];
                    r0p[cc] = ((gp & bsel) == 0u || w2v == th0) ? 0.f : v0s;
                    float v1s = (w2v > th1) ? Fp1 * Bj[jj] : Fn1 * Bp8[jj];
                    r1p[cc] = ((gq & bsel) == 0u || w2v == th1) ? 0.f : v1s;
                }
                auto pr0 = __builtin_amdgcn_cvt_pkrtz(r0p[0], r0p[1]);
                af0[qq*2] = (_Float16)pr0[0]; af0[qq*2+1] = (_Float16)pr0[1];
                auto pr1 = __builtin_amdgcn_cvt_pkrtz(r1p[0], r1p[1]);
                af1[qq*2] = (_Float16)pr1[0]; af1[qq*2+1] = (_Float16)pr1[1];
            }
            a0 = __builtin_amdgcn_mfma_f32_16x16x32_f16(af0, bb, a0, 0, 0, 0);
            l0 = __builtin_amdgcn_mfma_f32_16x16x32_f16(af0, ones, l0, 0, 0, 0);
            a1 = __builtin_amdgcn_mfma_f32_16x16x32_f16(af1, bb, a1, 0, 0, 0);
            l1 = __builtin_amdgcn_mfma_f32_16x16x32_f16(af1, ones, l1, 0, 0, 0);
        }
    }
#pragma unroll
    for (int reg = 0; reg < 4; ++reg) {
        accred[wv][quad * 4 + reg][m] = a0[reg];
        accred[wv][quad * 4 + reg + 16][m] = a1[reg];
    }
    if (m == 0) {
#pragma unroll
        for (int reg = 0; reg < 4; ++reg) {
            lred[wv][quad * 4 + reg] = l0[reg];
            lred[wv][quad * 4 + reg + 16] = l1[reg];
        }
    }
    __syncthreads();
    const int row = tid >> 4, col = tid & 15;
    float s0 = accred[0][row][col] + accred[1][row][col]
             + accred[2][row][col] + accred[3][row][col];
    float s1 = accred[0][row + 16][col] + accred[1][row + 16][col]
             + accred[2][row + 16][col] + accred[3][row + 16][col];
    float* op = outp + (((size_t)split * B_ + b) * N_ + i0) * EN_;
    op[(size_t)row * EN_ + col] = s0;
    op[(size_t)(row + 16) * EN_ + col] = s1;
    if (tid < 32) {
        float l = lred[0][tid] + lred[1][tid] + lred[2][tid] + lred[3][tid];
        outlp[((size_t)split * B_ + b) * N_ + i0 + tid] = l;
    }
}

// ---------- final: sum split partials, divide, ELU
__global__ __launch_bounds__(256) void finalize2_kernel(
    const float* __restrict__ outp, const float* __restrict__ outlp,
    float* __restrict__ out)
{
    const int id = blockIdx.x * 256 + threadIdx.x;      // B*N*EN
    const int gi = id >> 4;
    float num = 0.f, l = 0.f;
#pragma unroll
    for (int s = 0; s < S2_; ++s) {
        num += outp[(size_t)s * B_ * N_ * EN_ + id];
        l   += outlp[(size_t)s * B_ * N_ + gi];
    }
    float v = num / fmaxf(l, 1e-30f);
    out[id] = v > 0.f ? v : expm1f(v);
}

extern "C" void kernel_launch(void* const* d_in, const int* in_sizes, int n_in,
                              void* d_out, int out_size, void* d_ws, size_t ws_size,
                              hipStream_t stream)
{
    const float* fea = (const float*)d_in[0];
    const float* adj = (const float*)d_in[1];
    const float* Wh  = (const float*)d_in[2];
    const float* ah  = (const float*)d_in[3];
    const float* Wl  = (const float*)d_in[4];
    const float* al  = (const float*)d_in[5];

    float* p = (float*)d_ws;
    float* wh1   = p;  p += (size_t)B_ * H_ * N_;            // 32768
    float* wh2   = p;  p += (size_t)B_ * H_ * N_;            // 32768
    float* wh1b  = p;  p += (size_t)B_ * N_;                 // 8192
    float* wh2b  = p;  p += (size_t)B_ * N_;                 // 8192
    float* cmax1 = p;  p += (size_t)B_ * H_ * 128;           // 1024
    float* cmax2 = p;  p += (size_t)B_ * 256;                // 512
    float* l1p   = p;  p += (size_t)S1_ * B_ * N_ * H_;      // 131072
    float* x2p   = p;  p += (size_t)S1_ * B_ * N_ * D_;      // 4194304
    float* outp  = p;  p += (size_t)S2_ * B_ * N_ * EN_;     // 524288
    float* outlp = p;  p += (size_t)S2_ * B_ * N_;           // 32768
    unsigned long long* mask = (unsigned long long*)p;       // B*N*64 u64 = 4 MB
    unsigned short* whTt  = (unsigned short*)(mask + (size_t)B_ * N_ * 64);  // 2 MB
    unsigned short* whT2t = whTt + (size_t)B_ * H_ * 131072;                 // 256 KB

    prep_kernel<<<2048 + B_ * H_ * 128, 256, 0, stream>>>(adj, mask, fea, Wh, ah,
                                                          wh1, wh2, cmax1, whTt);
    attn1_kernel<<<dim3(N_ / 32, S1_, B_), 256, 0, stream>>>(mask, whTt, wh1, wh2, cmax1,
                                                             x2p, l1p);
    proj2_kernel<<<dim3(N_ / 16, B_), 256, 0, stream>>>(x2p, l1p, Wl, al,
                                                        wh1b, wh2b, cmax2, whT2t);
    attn2_kernel<<<dim3(N_ / 32, S2_, B_), 256, 0, stream>>>(mask, whT2t, wh1b, wh2b, cmax2,
                                                             outp, outlp);
    finalize2_kernel<<<(B_ * N_ * EN_) / 256, 256, 0, stream>>>(outp, outlp, (float*)d_out);
}

// Round 5
// 276.332 us; speedup vs baseline: 1.0048x; 1.0048x over previous
//
#include <hip/hip_runtime.h>
#include <hip/hip_bf16.h>
#include <stdint.h>

#define B_ 2
#define N_ 4096
#define D_ 128
#define H_ 4
#define HID_ 32
#define EN_ 16
#define ALPHA_ 0.2f
#define S1_ 4
#define S2_ 4
#define LOG2E_ 1.4426950408889634f

typedef __attribute__((ext_vector_type(8))) _Float16 f16x8;
typedef __attribute__((ext_vector_type(4))) float f32x4;
typedef __attribute__((ext_vector_type(8))) unsigned short u16x8;

__device__ __forceinline__ unsigned short f2h(float v) {
    _Float16 h = (_Float16)v;
    return *(unsigned short*)&h;
}

// ---------- fused prep: blocks [0,2048) = adj->bitmask; [2048,3072) = layer-1 proj.
__global__ __launch_bounds__(256) void prep_kernel(
    const float* __restrict__ adj, unsigned long long* __restrict__ mask,
    const float* __restrict__ fea, const float* __restrict__ Wh,
    const float* __restrict__ a_heads,
    float* __restrict__ wh1, float* __restrict__ wh2,
    float* __restrict__ cmax1, unsigned short* __restrict__ whTt)
{
    __shared__ float xs[32][132];          // 16.9 KB
    __shared__ float WT[32][132];          // 16.9 KB
    __shared__ float Wa[2][128];
    __shared__ float as_[2 * HID_];
    __shared__ unsigned short ts[32][32];  // [d][r]
    __shared__ float rmax[32];
    const int tid = threadIdx.x;

    if (blockIdx.x < 2048) {               // ---- mask part ----
        const int b = blockIdx.x >> 10, ib = blockIdx.x & 1023;
        const int i = ib * 4 + (tid >> 6);
        const int lane = tid & 63;
        const float* ar = adj + ((size_t)b * N_ + i) * N_;
        unsigned long long* mrow = mask + ((size_t)b * N_ + i) * 64;
#pragma unroll 4
        for (int c = 0; c < 16; ++c) {
            float4 v = *(const float4*)(ar + c * 256 + lane * 4);
            unsigned long long b0 = __ballot(v.x != 0.f);
            unsigned long long b1 = __ballot(v.y != 0.f);
            unsigned long long b2 = __ballot(v.z != 0.f);
            unsigned long long b3 = __ballot(v.w != 0.f);
            if (lane == 0) {
                ulonglong2 w01 = {b0, b1}, w23 = {b2, b3};
                *(ulonglong2*)(mrow + c * 4) = w01;
                *(ulonglong2*)(mrow + c * 4 + 2) = w23;
            }
        }
        return;
    }
    // ---- proj1 part: 32 rows x 32 cols, one head ----
    const int l0 = blockIdx.x - 2048;
    const int ib = l0 & 127, h = (l0 >> 7) & 3, b = l0 >> 9;
    const int i0 = ib * 32;
    const float* Wp = Wh + (size_t)h * D_ * HID_;
    for (int l = tid; l < 1024; l += 256) {          // W[k][d] -> WT[d][k]
        float4 w4 = *(const float4*)(Wp + l * 4);
        int k = l >> 3, d = (l & 7) * 4;
        WT[d][k] = w4.x; WT[d + 1][k] = w4.y; WT[d + 2][k] = w4.z; WT[d + 3][k] = w4.w;
    }
    if (tid < 2 * HID_) as_[tid] = a_heads[h * 2 * HID_ + tid];
    const float* xp = fea + ((size_t)b * N_ + i0) * D_;
    for (int l = tid; l < 1024; l += 256) {
        int r = l >> 5, k4 = (l & 31) * 4;
        *(float4*)&xs[r][k4] = *(const float4*)(xp + r * D_ + k4);
    }
    __syncthreads();
    // Wa[j][k] = sum_d W[k][d]*a[j*HID+d]
    {
        const int k = tid & 127, j = tid >> 7;
        const float* wr = Wp + k * HID_;
        const float* aw = &as_[j * HID_];
        float s = 0.f;
#pragma unroll
        for (int d = 0; d < HID_; d += 4) {
            float4 w4 = *(const float4*)(wr + d);
            s += w4.x * aw[d] + w4.y * aw[d + 1] + w4.z * aw[d + 2] + w4.w * aw[d + 3];
        }
        Wa[j][k] = s;
    }
    const int c = tid & 15, rg = (tid >> 4) * 2;     // rows rg,rg+1; cols c,c+16
    float a0[2] = {0.f, 0.f}, a1[2] = {0.f, 0.f};
#pragma unroll 8
    for (int k = 0; k < D_; k += 4) {
        float4 w0 = *(float4*)&WT[c][k];
        float4 w1 = *(float4*)&WT[c + 16][k];
#pragma unroll
        for (int i = 0; i < 2; ++i) {
            float4 x4 = *(float4*)&xs[rg + i][k];
            a0[i] += x4.x * w0.x + x4.y * w0.y + x4.z * w0.z + x4.w * w0.w;
            a1[i] += x4.x * w1.x + x4.y * w1.y + x4.z * w1.z + x4.w * w1.w;
        }
    }
#pragma unroll
    for (int i = 0; i < 2; ++i) {
        ts[c][rg + i] = f2h(a0[i]);
        ts[c + 16][rg + i] = f2h(a1[i]);
    }
    __syncthreads();                                 // Wa + ts ready
    {
        const int row = tid >> 3, q = tid & 7;       // 32 rows x 8 threads
        float d1 = 0.f, d2 = 0.f;
#pragma unroll
        for (int k = q * 16; k < q * 16 + 16; k += 4) {
            float4 x4 = *(float4*)&xs[row][k];
            float4 u = *(float4*)&Wa[0][k];
            float4 v = *(float4*)&Wa[1][k];
            d1 += x4.x * u.x + x4.y * u.y + x4.z * u.z + x4.w * u.w;
            d2 += x4.x * v.x + x4.y * v.y + x4.z * v.z + x4.w * v.w;
        }
        d1 += __shfl_xor(d1, 1); d1 += __shfl_xor(d1, 2); d1 += __shfl_xor(d1, 4);
        d2 += __shfl_xor(d2, 1); d2 += __shfl_xor(d2, 2); d2 += __shfl_xor(d2, 4);
        if (q == 0) {
            const size_t o = (size_t)(b * H_ + h) * N_ + i0 + row;
            wh1[o] = d1 * LOG2E_;
            wh2[o] = d2 * LOG2E_;
            rmax[row] = d2 * LOG2E_;
        }
    }
    __syncthreads();
    if (tid < 128) {                                 // whT tile out (1024 halfwords)
        const int d = tid >> 2, part = (tid & 3) * 8;
        unsigned short* dst = whTt + ((size_t)(b * H_ + h) * 64 + (i0 >> 6)) * 2048
                            + d * 64 + (i0 & 63) + part;
        *(u16x8*)dst = *(u16x8*)&ts[d][part];
    }
    if (tid < 32) {
        float mx = rmax[tid];
#pragma unroll
        for (int off = 16; off; off >>= 1) mx = fmaxf(mx, __shfl_xor(mx, off));
        if (tid == 0) cmax1[(size_t)(b * H_ + h) * 128 + ib] = mx;
    }
}

// ---------- layer-1 fused MFMA attention.
// PROBE (R5): no min-waves bound -> compiler free up to 512 VGPR, zero forced
// spills. If caps 128 (R1-R3) AND ~170 (R4) were BOTH spilling (their mutual
// neutrality is consistent with that), this removes scratch entirely. LDS
// still permits 4 blocks/CU; VGPR may reduce to 2 blocks/CU (8 waves) which a
// throughput-bound loop tolerates.
__global__ __launch_bounds__(256) void attn1_kernel(
    const unsigned long long* __restrict__ mask, const unsigned short* __restrict__ whT,
    const float* __restrict__ wh1, const float* __restrict__ wh2,
    const float* __restrict__ cmax1,
    float* __restrict__ x2p, float* __restrict__ l1p)
{
    __shared__ unsigned long long mask_s[32][17];
    __shared__ float Btab[H_][2][1024];    // 32 KB: per-head (B, B') tables
    const int b = blockIdx.z, split = blockIdx.y, i0 = blockIdx.x * 32;
    const int tid = threadIdx.x, lane = tid & 63, h = tid >> 6;
    const int m = lane & 15, quad = lane >> 4;
    {
        const int r = tid >> 3, w = (tid & 7) * 2;
        ulonglong2 mw = *(const ulonglong2*)(mask + ((size_t)b * N_ + i0 + r) * 64
                                             + split * 16 + w);
        mask_s[r][w] = mw.x; mask_s[r][w + 1] = mw.y;
    }
    const float* cm = cmax1 + (size_t)(b * H_ + h) * 128;
    float Mh = fmaxf(cm[lane], cm[lane + 64]);
#pragma unroll
    for (int off = 32; off; off >>= 1) Mh = fmaxf(Mh, __shfl_xor(Mh, off));
    const size_t bhN = (size_t)(b * H_ + h) * N_;
    // fill this head's (B, B') table: 1024 j's, 16 per lane
    const float* w2g = wh2 + bhN + split * 1024;
#pragma unroll
    for (int g = 0; g < 4; ++g) {
        float4 v = *(const float4*)(w2g + g * 256 + lane * 4);
        float4 eb, ep;
        eb.x = __builtin_amdgcn_exp2f(v.x - Mh);
        eb.y = __builtin_amdgcn_exp2f(v.y - Mh);
        eb.z = __builtin_amdgcn_exp2f(v.z - Mh);
        eb.w = __builtin_amdgcn_exp2f(v.w - Mh);
        ep.x = __builtin_amdgcn_exp2f(ALPHA_ * (v.x - Mh));
        ep.y = __builtin_amdgcn_exp2f(ALPHA_ * (v.y - Mh));
        ep.z = __builtin_amdgcn_exp2f(ALPHA_ * (v.z - Mh));
        ep.w = __builtin_amdgcn_exp2f(ALPHA_ * (v.w - Mh));
        *(float4*)&Btab[h][0][g * 256 + lane * 4] = eb;
        *(float4*)&Btab[h][1][g * 256 + lane * 4] = ep;
    }
    const float w1r0 = wh1[bhN + i0 + m];
    const float w1r1 = wh1[bhN + i0 + 16 + m];
    const float sb0 = w1r0 + Mh, sb1 = w1r1 + Mh;
    const float mr0 = fmaxf(sb0, ALPHA_ * sb0);
    const float mr1 = fmaxf(sb1, ALPHA_ * sb1);
    const float th0 = -w1r0, th1 = -w1r1;
    const float Fp0 = __builtin_amdgcn_exp2f(sb0 - mr0);
    const float Fn0 = __builtin_amdgcn_exp2f(ALPHA_ * sb0 - mr0);
    const float Fp1 = __builtin_amdgcn_exp2f(sb1 - mr1);
    const float Fn1 = __builtin_amdgcn_exp2f(ALPHA_ * sb1 - mr1);
    const float* wvb = wh2 + bhN + split * 1024 + quad * 8;
    const unsigned short* bpb = whT + (size_t)(b * H_ + h) * 131072
                              + (size_t)split * 16 * 2048 + m * 64 + quad * 8;
    f32x4 a00 = {0.f,0.f,0.f,0.f}, a01 = {0.f,0.f,0.f,0.f}, a02 = {0.f,0.f,0.f,0.f};
    f32x4 a10 = {0.f,0.f,0.f,0.f}, a11 = {0.f,0.f,0.f,0.f}, a12 = {0.f,0.f,0.f,0.f};
    f16x8 ones;
#pragma unroll
    for (int q = 0; q < 8; ++q) ones[q] = (_Float16)1.0f;
    __syncthreads();

    for (int c = 0; c < 4; ++c) {
#pragma unroll
        for (int q4 = 0; q4 < 4; ++q4) {
            const int t = c * 4 + q4;
            const int half = q4 >> 1;                // dword half of the 64-bit word
            unsigned int pw0, pw1, pw2, pw3, qw0, qw1, qw2, qw3;
            pw0 = ((const unsigned int*)&mask_s[m][c*4+0])[half];
            pw1 = ((const unsigned int*)&mask_s[m][c*4+1])[half];
            pw2 = ((const unsigned int*)&mask_s[m][c*4+2])[half];
            pw3 = ((const unsigned int*)&mask_s[m][c*4+3])[half];
            qw0 = ((const unsigned int*)&mask_s[m+16][c*4+0])[half];
            qw1 = ((const unsigned int*)&mask_s[m+16][c*4+1])[half];
            qw2 = ((const unsigned int*)&mask_s[m+16][c*4+2])[half];
            qw3 = ((const unsigned int*)&mask_s[m+16][c*4+3])[half];
            const unsigned short* bp = bpb + (size_t)t * 2048;
            const float* nw = wvb + t * 64;
#pragma unroll
            for (int ks = 0; ks < 2; ++ks) {
                f16x8 bb0 = *(const f16x8*)(bp + ks * 32);
                f16x8 bb1 = *(const f16x8*)(bp + 1024 + ks * 32);
                float wv8[8];
                *(float4*)&wv8[0] = *(const float4*)(nw + ks * 32);
                *(float4*)&wv8[4] = *(const float4*)(nw + ks * 32 + 4);
                float Bj[8], Bp8[8];
                {
                    const float* Bb = &Btab[h][0][t * 64 + ks * 32 + quad * 8];
                    const float* Pb = &Btab[h][1][t * 64 + ks * 32 + quad * 8];
                    *(float4*)&Bj[0]  = *(const float4*)Bb;
                    *(float4*)&Bj[4]  = *(const float4*)(Bb + 4);
                    *(float4*)&Bp8[0] = *(const float4*)Pb;
                    *(float4*)&Bp8[4] = *(const float4*)(Pb + 4);
                }
                const int sh = ((16 * q4 + 8 * ks) & 31) + 2 * quad;
                const unsigned int gp0 = (pw0 >> sh) & 3u;
                const unsigned int gp1 = (pw1 >> sh) & 3u;
                const unsigned int gp2 = (pw2 >> sh) & 3u;
                const unsigned int gp3 = (pw3 >> sh) & 3u;
                const unsigned int gq0 = (qw0 >> sh) & 3u;
                const unsigned int gq1 = (qw1 >> sh) & 3u;
                const unsigned int gq2 = (qw2 >> sh) & 3u;
                const unsigned int gq3 = (qw3 >> sh) & 3u;
                f16x8 af0, af1;
#pragma unroll
                for (int qq = 0; qq < 4; ++qq) {
                    float r0p[2], r1p[2];
#pragma unroll
                    for (int cc = 0; cc < 2; ++cc) {
                        const int jj = qq * 2 + cc;
                        const unsigned int bsel = 1u << (jj >> 2);
                        const unsigned int gp = (jj&3)==0?gp0:(jj&3)==1?gp1:(jj&3)==2?gp2:gp3;
                        const unsigned int gq = (jj&3)==0?gq0:(jj&3)==1?gq1:(jj&3)==2?gq2:gq3;
                        const float w2v = wv8[jj];
                        float v0s = (w2v > th0) ? Fp0 * Bj[jj] : Fn0 * Bp8[jj];
                        r0p[cc] = ((gp & bsel) == 0u || w2v == th0) ? 0.f : v0s;
                        float v1s = (w2v > th1) ? Fp1 * Bj[jj] : Fn1 * Bp8[jj];
                        r1p[cc] = ((gq & bsel) == 0u || w2v == th1) ? 0.f : v1s;
                    }
                    auto pr0 = __builtin_amdgcn_cvt_pkrtz(r0p[0], r0p[1]);
                    af0[qq*2] = (_Float16)pr0[0]; af0[qq*2+1] = (_Float16)pr0[1];
                    auto pr1 = __builtin_amdgcn_cvt_pkrtz(r1p[0], r1p[1]);
                    af1[qq*2] = (_Float16)pr1[0]; af1[qq*2+1] = (_Float16)pr1[1];
                }
                a00 = __builtin_amdgcn_mfma_f32_16x16x32_f16(af0, bb0, a00, 0, 0, 0);
                a01 = __builtin_amdgcn_mfma_f32_16x16x32_f16(af0, bb1, a01, 0, 0, 0);
                a02 = __builtin_amdgcn_mfma_f32_16x16x32_f16(af0, ones, a02, 0, 0, 0);
                a10 = __builtin_amdgcn_mfma_f32_16x16x32_f16(af1, bb0, a10, 0, 0, 0);
                a11 = __builtin_amdgcn_mfma_f32_16x16x32_f16(af1, bb1, a11, 0, 0, 0);
                a12 = __builtin_amdgcn_mfma_f32_16x16x32_f16(af1, ones, a12, 0, 0, 0);
            }
        }
    }
    float* xp = x2p + (((size_t)split * B_ + b) * N_ + i0) * D_ + h * HID_;
#pragma unroll
    for (int reg = 0; reg < 4; ++reg) {
        const int row = quad * 4 + reg;
        xp[(size_t)row * D_ + m] = a00[reg];
        xp[(size_t)row * D_ + 16 + m] = a01[reg];
        xp[(size_t)(row + 16) * D_ + m] = a10[reg];
        xp[(size_t)(row + 16) * D_ + 16 + m] = a11[reg];
    }
    if (m == 0) {
        float* lp = l1p + (((size_t)split * B_ + b) * N_ + i0) * H_ + h;
#pragma unroll
        for (int reg = 0; reg < 4; ++reg) {
            lp[(size_t)(quad * 4 + reg) * H_] = a02[reg];
            lp[(size_t)(quad * 4 + reg + 16) * H_] = a12[reg];
        }
    }
}

// ---------- merged layer-2 projection (unchanged)
__global__ __launch_bounds__(256) void proj2_kernel(
    const float* __restrict__ x2p, const float* __restrict__ l1p,
    const float* __restrict__ Wl, const float* __restrict__ a_last,
    float* __restrict__ wh1b, float* __restrict__ wh2b,
    float* __restrict__ cmax2, unsigned short* __restrict__ whT2t)
{
    __shared__ float Ws[D_ * EN_];
    __shared__ float xs[16][D_];
    __shared__ float as_[2 * EN_];
    __shared__ unsigned short ts[EN_][16];
    __shared__ float rmax[16];
    const int b = blockIdx.y, i0 = blockIdx.x * 16, tid = threadIdx.x;
    for (int idx = tid * 4; idx < D_ * EN_; idx += 1024)
        *(float4*)&Ws[idx] = *(const float4*)(Wl + idx);
    if (tid < 2 * EN_) as_[tid] = a_last[tid];
    for (int idx = tid * 4; idx < 16 * D_; idx += 1024) {
        const int r = idx >> 7, hd = idx & 127, h = hd >> 5;
        float4 v = {0.f, 0.f, 0.f, 0.f};
        float l = 0.f;
#pragma unroll
        for (int s = 0; s < S1_; ++s) {
            const size_t gi = ((size_t)s * B_ + b) * N_ + i0 + r;
            float4 p = *(const float4*)(x2p + gi * D_ + hd);
            v.x += p.x; v.y += p.y; v.z += p.z; v.w += p.w;
            l += l1p[gi * H_ + h];
        }
        float linv = 1.f / fmaxf(l, 1e-30f);
        float o0 = v.x * linv, o1 = v.y * linv, o2 = v.z * linv, o3 = v.w * linv;
        xs[r][hd]     = o0 > 0.f ? o0 : expm1f(o0);
        xs[r][hd + 1] = o1 > 0.f ? o1 : expm1f(o1);
        xs[r][hd + 2] = o2 > 0.f ? o2 : expm1f(o2);
        xs[r][hd + 3] = o3 > 0.f ? o3 : expm1f(o3);
    }
    __syncthreads();
    const int r = tid >> 4, e = tid & 15;
    float acc = 0.f;
#pragma unroll 8
    for (int k = 0; k < D_; ++k) acc += xs[r][k] * Ws[k * EN_ + e];
    ts[e][r] = f2h(acc);
    float d1 = acc * as_[e], d2 = acc * as_[EN_ + e];
#pragma unroll
    for (int off = 8; off; off >>= 1) {
        d1 += __shfl_xor(d1, off);
        d2 += __shfl_xor(d2, off);
    }
    d1 *= LOG2E_; d2 *= LOG2E_;
    if (e == 0) {
        wh1b[(size_t)b * N_ + i0 + r] = d1;
        wh2b[(size_t)b * N_ + i0 + r] = d2;
        rmax[r] = d2;
    }
    __syncthreads();
    if (tid < EN_) {
        unsigned short* dst = whT2t + (size_t)b * 65536
                            + (i0 >> 6) * 1024 + tid * 64 + (i0 & 63);
        *(u16x8*)dst = *(u16x8*)&ts[tid][0];
        *(u16x8*)(dst + 8) = *(u16x8*)&ts[tid][8];
    }
    if (tid == 0) {
        float mx = rmax[0];
#pragma unroll
        for (int k = 1; k < 16; ++k) mx = fmaxf(mx, rmax[k]);
        cmax2[(size_t)b * 256 + blockIdx.x] = mx;
    }
}

// ---------- layer-2 fused MFMA attention (same no-min-bound probe)
__global__ __launch_bounds__(256) void attn2_kernel(
    const unsigned long long* __restrict__ mask, const unsigned short* __restrict__ whT2,
    const float* __restrict__ wh1b, const float* __restrict__ wh2b,
    const float* __restrict__ cmax2,
    float* __restrict__ outp, float* __restrict__ outlp)
{
    __shared__ unsigned long long mask_s[32][17];
    __shared__ float accred[4][32][17];
    __shared__ float lred[4][32];
    __shared__ float Btab2[2][1024];       // 8 KB
    const int b = blockIdx.z, split = blockIdx.y, i0 = blockIdx.x * 32;
    const int tid = threadIdx.x, lane = tid & 63, wv = tid >> 6;
    const int m = lane & 15, quad = lane >> 4;
    {
        const int r = tid >> 3, w = (tid & 7) * 2;
        ulonglong2 mw = *(const ulonglong2*)(mask + ((size_t)b * N_ + i0 + r) * 64
                                             + split * 16 + w);
        mask_s[r][w] = mw.x; mask_s[r][w + 1] = mw.y;
    }
    const float* cm = cmax2 + (size_t)b * 256;
    float4 c0 = *(const float4*)(cm + lane * 4);
    float Mh = fmaxf(fmaxf(c0.x, c0.y), fmaxf(c0.z, c0.w));
#pragma unroll
    for (int off = 32; off; off >>= 1) Mh = fmaxf(Mh, __shfl_xor(Mh, off));
    // fill shared (B, B') table: 4 j's per thread
    {
        float4 v = *(const float4*)(wh2b + (size_t)b * N_ + split * 1024 + tid * 4);
        float4 eb, ep;
        eb.x = __builtin_amdgcn_exp2f(v.x - Mh);
        eb.y = __builtin_amdgcn_exp2f(v.y - Mh);
        eb.z = __builtin_amdgcn_exp2f(v.z - Mh);
        eb.w = __builtin_amdgcn_exp2f(v.w - Mh);
        ep.x = __builtin_amdgcn_exp2f(ALPHA_ * (v.x - Mh));
        ep.y = __builtin_amdgcn_exp2f(ALPHA_ * (v.y - Mh));
        ep.z = __builtin_amdgcn_exp2f(ALPHA_ * (v.z - Mh));
        ep.w = __builtin_amdgcn_exp2f(ALPHA_ * (v.w - Mh));
        *(float4*)&Btab2[0][tid * 4] = eb;
        *(float4*)&Btab2[1][tid * 4] = ep;
    }
    const float w1r0 = wh1b[(size_t)b * N_ + i0 + m];
    const float w1r1 = wh1b[(size_t)b * N_ + i0 + 16 + m];
    const float sb0 = w1r0 + Mh, sb1 = w1r1 + Mh;
    const float mr0 = fmaxf(sb0, ALPHA_ * sb0);
    const float mr1 = fmaxf(sb1, ALPHA_ * sb1);
    const float th0 = -w1r0, th1 = -w1r1;
    const float Fp0 = __builtin_amdgcn_exp2f(sb0 - mr0);
    const float Fn0 = __builtin_amdgcn_exp2f(ALPHA_ * sb0 - mr0);
    const float Fp1 = __builtin_amdgcn_exp2f(sb1 - mr1);
    const float Fn1 = __builtin_amdgcn_exp2f(ALPHA_ * sb1 - mr1);
    const unsigned short* wTb = whT2 + (size_t)b * 65536
                              + (size_t)(split * 16 + wv * 4) * 1024 + m * 64 + quad * 8;
    const float* wvb = wh2b + (size_t)b * N_ + split * 1024 + wv * 256 + quad * 8;
    f32x4 a0 = {0.f,0.f,0.f,0.f}, a1 = {0.f,0.f,0.f,0.f};
    f32x4 l0 = {0.f,0.f,0.f,0.f}, l1 = {0.f,0.f,0.f,0.f};
    f16x8 ones;
#pragma unroll
    for (int q = 0; q < 8; ++q) ones[q] = (_Float16)1.0f;
    __syncthreads();
#pragma unroll
    for (int q4 = 0; q4 < 4; ++q4) {
        const int half = q4 >> 1;
        unsigned int pw0, pw1, pw2, pw3, qw0, qw1, qw2, qw3;
        pw0 = ((const unsigned int*)&mask_s[m][wv*4+0])[half];
        pw1 = ((const unsigned int*)&mask_s[m][wv*4+1])[half];
        pw2 = ((const unsigned int*)&mask_s[m][wv*4+2])[half];
        pw3 = ((const unsigned int*)&mask_s[m][wv*4+3])[half];
        qw0 = ((const unsigned int*)&mask_s[m+16][wv*4+0])[half];
        qw1 = ((const unsigned int*)&mask_s[m+16][wv*4+1])[half];
        qw2 = ((const unsigned int*)&mask_s[m+16][wv*4+2])[half];
        qw3 = ((const unsigned int*)&mask_s[m+16][wv*4+3])[half];
        const unsigned short* bp = wTb + (size_t)q4 * 1024;
        const float* nw = wvb + q4 * 64;
#pragma unroll
        for (int ks = 0; ks < 2; ++ks) {
            f16x8 bb = *(const f16x8*)(bp + ks * 32);
            float wv8[8];
            *(float4*)&wv8[0] = *(const float4*)(nw + ks * 32);
            *(float4*)&wv8[4] = *(const float4*)(nw + ks * 32 + 4);
            float Bj[8], Bp8[8];
            {
                const float* Bb = &Btab2[0][wv * 256 + q4 * 64 + ks * 32 + quad * 8];
                const float* Pb = &Btab2[1][wv * 256 + q4 * 64 + ks * 32 + quad * 8];
                *(float4*)&Bj[0]  = *(const float4*)Bb;
                *(float4*)&Bj[4]  = *(const float4*)(Bb + 4);
                *(float4*)&Bp8[0] = *(const float4*)Pb;
                *(float4*)&Bp8[4] = *(const float4*)(Pb + 4);
            }
            const int sh = ((16 * q4 + 8 * ks) & 31) + 2 * quad;
            const unsigned int gp0 = (pw0 >> sh) & 3u;
            const unsigned int gp1 = (pw1 >> sh) & 3u;
            const unsigned int gp2 = (pw2 >> sh) & 3u;
            const unsigned int gp3 = (pw3 >> sh) & 3u;
            const unsigned int gq0 = (qw0 >> sh) & 3u;
            const unsigned int gq1 = (qw1 >> sh) & 3u;
            const unsigned int gq2 = (qw2 >> sh) & 3u;
            const unsigned int gq3 = (qw3 >> sh) & 3u;
            f16x8 af0, af1;
#pragma unroll
            for (int qq = 0; qq < 4; ++qq) {
                float r0p[2], r1p[2];
#pragma unroll
                for (int cc = 0; cc < 2; ++cc) {
                    const int jj = qq * 2 + cc;
                    const unsigned int bsel = 1u << (jj >> 2);
                    const unsigned int gp = (jj&3)==0?gp0:(jj&3)==1?gp1:(jj&3)==2?gp2:gp3;
                    const unsigned int gq = (jj&3)==0?gq0:(jj&3)==1?gq1:(jj&3)==2?gq2:gq3;
                    const float w2v = wv8[jj];
                    float v0s = (w2v > th0) ? Fp0 * Bj[jj] : Fn0 * Bp8[jj];
                    r0p[cc] = ((gp & bsel) == 0u || w2v == th0) ? 0.f : v0s;
                    float v1s = (w2v > th1) ? Fp1 * Bj[jj] : Fn1 * Bp8[jj];
                    r1p[cc] = ((gq & bsel) == 0u || w2v == th1) ? 0.f : v1s;
                }
                auto pr0 = __builtin_amdgcn_cvt_pkrtz(r0p[0], r0p[1]);
                af0[qq*2] = (_Float16)pr0[0]; af0[qq*2+1] = (_Float16)pr0[1];
                auto pr1 = __builtin_amdgcn_cvt_pkrtz(r1p[0], r1p[1]);
                af1[qq*2] = (_Float16)pr1[0]; af1[qq*2+1] = (_Float16)pr1[1];
            }
            a0 = __builtin_amdgcn_mfma_f32_16x16x32_f16(af0, bb, a0, 0, 0, 0);
            l0 = __builtin_amdgcn_mfma_f32_16x16x32_f16(af0, ones, l0, 0, 0, 0);
            a1 = __builtin_amdgcn_mfma_f32_16x16x32_f16(af1, bb, a1, 0, 0, 0);
            l1 = __builtin_amdgcn_mfma_f32_16x16x32_f16(af1, ones, l1, 0, 0, 0);
        }
    }
#pragma unroll
    for (int reg = 0; reg < 4; ++reg) {
        accred[wv][quad * 4 + reg][m] = a0[reg];
        accred[wv][quad * 4 + reg + 16][m] = a1[reg];
    }
    if (m == 0) {
#pragma unroll
        for (int reg = 0; reg < 4; ++reg) {
            lred[wv][quad * 4 + reg] = l0[reg];
            lred[wv][quad * 4 + reg + 16] = l1[reg];
        }
    }
    __syncthreads();
    const int row = tid >> 4, col = tid & 15;
    float s0 = accred[0][row][col] + accred[1][row][col]
             + accred[2][row][col] + accred[3][row][col];
    float s1 = accred[0][row + 16][col] + accred[1][row + 16][col]
             + accred[2][row + 16][col] + accred[3][row + 16][col];
    float* op = outp + (((size_t)split * B_ + b) * N_ + i0) * EN_;
    op[(size_t)row * EN_ + col] = s0;
    op[(size_t)(row + 16) * EN_ + col] = s1;
    if (tid < 32) {
        float l = lred[0][tid] + lred[1][tid] + lred[2][tid] + lred[3][tid];
        outlp[((size_t)split * B_ + b) * N_ + i0 + tid] = l;
    }
}

// ---------- final: sum split partials, divide, ELU
__global__ __launch_bounds__(256) void finalize2_kernel(
    const float* __restrict__ outp, const float* __restrict__ outlp,
    float* __restrict__ out)
{
    const int id = blockIdx.x * 256 + threadIdx.x;      // B*N*EN
    const int gi = id >> 4;
    float num = 0.f, l = 0.f;
#pragma unroll
    for (int s = 0; s < S2_; ++s) {
        num += outp[(size_t)s * B_ * N_ * EN_ + id];
        l   += outlp[(size_t)s * B_ * N_ + gi];
    }
    float v = num / fmaxf(l, 1e-30f);
    out[id] = v > 0.f ? v : expm1f(v);
}

extern "C" void kernel_launch(void* const* d_in, const int* in_sizes, int n_in,
                              void* d_out, int out_size, void* d_ws, size_t ws_size,
                              hipStream_t stream)
{
    const float* fea = (const float*)d_in[0];
    const float* adj = (const float*)d_in[1];
    const float* Wh  = (const float*)d_in[2];
    const float* ah  = (const float*)d_in[3];
    const float* Wl  = (const float*)d_in[4];
    const float* al  = (const float*)d_in[5];

    float* p = (float*)d_ws;
    float* wh1   = p;  p += (size_t)B_ * H_ * N_;            // 32768
    float* wh2   = p;  p += (size_t)B_ * H_ * N_;            // 32768
    float* wh1b  = p;  p += (size_t)B_ * N_;                 // 8192
    float* wh2b  = p;  p += (size_t)B_ * N_;                 // 8192
    float* cmax1 = p;  p += (size_t)B_ * H_ * 128;           // 1024
    float* cmax2 = p;  p += (size_t)B_ * 256;                // 512
    float* l1p   = p;  p += (size_t)S1_ * B_ * N_ * H_;      // 131072
    float* x2p   = p;  p += (size_t)S1_ * B_ * N_ * D_;      // 4194304
    float* outp  = p;  p += (size_t)S2_ * B_ * N_ * EN_;     // 524288
    float* outlp = p;  p += (size_t)S2_ * B_ * N_;           // 32768
    unsigned long long* mask = (unsigned long long*)p;       // B*N*64 u64 = 4 MB
    unsigned short* whTt  = (unsigned short*)(mask + (size_t)B_ * N_ * 64);  // 2 MB
    unsigned short* whT2t = whTt + (size_t)B_ * H_ * 131072;                 // 256 KB

    prep_kernel<<<2048 + B_ * H_ * 128, 256, 0, stream>>>(adj, mask, fea, Wh, ah,
                                                          wh1, wh2, cmax1, whTt);
    attn1_kernel<<<dim3(N_ / 32, S1_, B_), 256, 0, stream>>>(mask, whTt, wh1, wh2, cmax1,
                                                             x2p, l1p);
    proj2_kernel<<<dim3(N_ / 16, B_), 256, 0, stream>>>(x2p, l1p, Wl, al,
                                                        wh1b, wh2b, cmax2, whT2t);
    attn2_kernel<<<dim3(N_ / 32, S2_, B_), 256, 0, stream>>>(mask, whT2t, wh1b, wh2b, cmax2,
                                                             outp, outlp);
    finalize2_kernel<<<(B_ * N_ * EN_) / 256, 256, 0, stream>>>(outp, outlp, (float*)d_out);
}